// Round 2
// baseline (231.667 us; speedup 1.0000x reference)
//
#include <hip/hip_runtime.h>

// Problem constants (fixed by setup_inputs)
static constexpr int B_ = 256;
static constexpr int T_ = 16384;
static constexpr int THREADS = 256;
static constexpr int SEG_T = 2048;                    // timesteps per block
static constexpr int NSEG = T_ / SEG_T;               // 8 segments per row
static constexpr int NBLK = B_ * NSEG;                // 2048 blocks
static constexpr int F4_PER_ROW = T_ * 2 / 4;         // 8192 float4 per b-row
static constexpr int F4_PER_SEG = SEG_T * 2 / 4;      // 1024 float4 per segment
static constexpr int F4_PER_THR = F4_PER_SEG / THREADS; // 4 float4 (8 timesteps) per thread

static constexpr float DTc    = 0.01f;
static constexpr float MINVAR = 0.01f;
static constexpr float EPSc   = 1e-6f;

// ws layout: [0..3] double accumulators {pos_sq, vel_sq, lc, reg}; +64B: float2 segsum[NBLK]

__device__ __forceinline__ float waveReduce(float v) {
#pragma unroll
  for (int d = 32; d > 0; d >>= 1) v += __shfl_down(v, d, 64);
  return v;
}

__global__ __launch_bounds__(THREADS) void kernA(
    const float4* __restrict__ vel, const float4* __restrict__ cov,
    const float4* __restrict__ vgt, double* __restrict__ acc,
    float2* __restrict__ segsum) {
  const int bid = blockIdx.x;
  const int b = bid >> 3, s = bid & (NSEG - 1);
  const int tid = threadIdx.x;
  const int base = b * F4_PER_ROW + s * F4_PER_SEG + tid * F4_PER_THR;

  float4 v[4], c[4], g[4];
#pragma unroll
  for (int i = 0; i < 4; ++i) v[i] = vel[base + i];
#pragma unroll
  for (int i = 0; i < 4; ++i) c[i] = cov[base + i];
#pragma unroll
  for (int i = 0; i < 4; ++i) g[i] = vgt[base + i];

  float sumx = 0.f, sumy = 0.f;       // chunk sum of vel (for scan)
  float lve = 0.f, lc = 0.f, reg = 0.f;
#pragma unroll
  for (int i = 0; i < 4; ++i) {
    sumx += v[i].x + v[i].z;
    sumy += v[i].y + v[i].w;
    {
      float dx = g[i].x - v[i].x, dy = g[i].y - v[i].y;
      float sqx = dx * dx, sqy = dy * dy;
      lve += sqx + sqy;
      float sx = fmaxf(__expf(c[i].x), MINVAR);
      float sy = fmaxf(__expf(c[i].y), MINVAR);
      float ix = 1.0f / sx, iy = 1.0f / sy;
      lc += ix * sqx + iy * sqy + __logf(sx * sy + EPSc);
      reg += ix + iy;
    }
    {
      float dx = g[i].z - v[i].z, dy = g[i].w - v[i].w;
      float sqx = dx * dx, sqy = dy * dy;
      lve += sqx + sqy;
      float sx = fmaxf(__expf(c[i].z), MINVAR);
      float sy = fmaxf(__expf(c[i].w), MINVAR);
      float ix = 1.0f / sx, iy = 1.0f / sy;
      lc += ix * sqx + iy * sqy + __logf(sx * sy + EPSc);
      reg += ix + iy;
    }
  }

  const int lane = tid & 63, wid = tid >> 6;
  float rx = waveReduce(sumx);
  float ry = waveReduce(sumy);
  float r1 = waveReduce(lve);
  float r2 = waveReduce(lc);
  float r3 = waveReduce(reg);
  __shared__ float sh[5][4];
  if (lane == 0) { sh[0][wid] = rx; sh[1][wid] = ry; sh[2][wid] = r1; sh[3][wid] = r2; sh[4][wid] = r3; }
  __syncthreads();
  if (tid == 0) {
    segsum[bid] = make_float2(sh[0][0] + sh[0][1] + sh[0][2] + sh[0][3],
                              sh[1][0] + sh[1][1] + sh[1][2] + sh[1][3]);
    atomicAdd(&acc[1], (double)(sh[2][0] + sh[2][1] + sh[2][2] + sh[2][3]));
    atomicAdd(&acc[2], (double)(sh[3][0] + sh[3][1] + sh[3][2] + sh[3][3]));
    atomicAdd(&acc[3], (double)(sh[4][0] + sh[4][1] + sh[4][2] + sh[4][3]));
  }
}

__global__ __launch_bounds__(THREADS) void kernB(
    const float4* __restrict__ vel, const float4* __restrict__ pgt,
    const float2* __restrict__ segsum, double* __restrict__ acc) {
  const int bid = blockIdx.x;
  const int b = bid >> 3, s = bid & (NSEG - 1);
  const int tid = threadIdx.x;
  const int lane = tid & 63, wid = tid >> 6;
  const int base = b * F4_PER_ROW + s * F4_PER_SEG + tid * F4_PER_THR;

  float4 v[4], g[4];
#pragma unroll
  for (int i = 0; i < 4; ++i) v[i] = vel[base + i];
#pragma unroll
  for (int i = 0; i < 4; ++i) g[i] = pgt[base + i];

  float csx = 0.f, csy = 0.f;
#pragma unroll
  for (int i = 0; i < 4; ++i) { csx += v[i].x + v[i].z; csy += v[i].y + v[i].w; }

  // wave-level inclusive scan of per-thread chunk sums
  float ix = csx, iy = csy;
#pragma unroll
  for (int d = 1; d < 64; d <<= 1) {
    float tx = __shfl_up(ix, (unsigned)d, 64);
    float ty = __shfl_up(iy, (unsigned)d, 64);
    if (lane >= d) { ix += tx; iy += ty; }
  }
  __shared__ float2 wtot[4];
  if (lane == 63) wtot[wid] = make_float2(ix, iy);
  __syncthreads();

  float bx = ix - csx, by = iy - csy;   // exclusive within wave
  for (int w = 0; w < wid; ++w) { bx += wtot[w].x; by += wtot[w].y; }

  // add exclusive prefix of previous segments in this row
  const float2* ss = segsum + b * NSEG;
  for (int k = 0; k < s; ++k) { float2 t = ss[k]; bx += t.x; by += t.y; }

  const float2 v0 = ((const float2*)vel)[b * T_];

  float apos = 0.f;
#pragma unroll
  for (int i = 0; i < 4; ++i) {
    float px = DTc * (v0.x + bx), py = DTc * (v0.y + by);
    float ex = px - g[i].x, ey = py - g[i].y;
    apos += ex * ex + ey * ey;
    bx += v[i].x; by += v[i].y;
    px = DTc * (v0.x + bx); py = DTc * (v0.y + by);
    ex = px - g[i].z; ey = py - g[i].w;
    apos += ex * ex + ey * ey;
    bx += v[i].z; by += v[i].w;
  }

  float r = waveReduce(apos);
  __shared__ float sh[4];
  if (lane == 0) sh[wid] = r;
  __syncthreads();
  if (tid == 0) atomicAdd(&acc[0], (double)(sh[0] + sh[1] + sh[2] + sh[3]));
}

__global__ void kernC(const double* __restrict__ acc,
                      const float* __restrict__ pldv, const float* __restrict__ pldc,
                      float* __restrict__ out) {
  if (threadIdx.x == 0 && blockIdx.x == 0) {
    const double NBT2 = (double)B_ * (double)T_ * 2.0;
    const double NBT  = (double)B_ * (double)T_;
    double lv  = (acc[0] + acc[1]) / NBT2;
    double lc  = 0.5 * acc[2] / NBT;
    double reg = acc[3] / NBT;
    double ldv = (double)pldv[0], ldc = (double)pldc[0];
    double total = lv / (2.0 * exp(2.0 * ldv)) + lc / (2.0 * exp(2.0 * ldc))
                 + ldv + ldc + 0.01 * reg;
    out[0] = (float)total;
  }
}

extern "C" void kernel_launch(void* const* d_in, const int* in_sizes, int n_in,
                              void* d_out, int out_size, void* d_ws, size_t ws_size,
                              hipStream_t stream) {
  const float4* vel = (const float4*)d_in[0];
  const float4* cov = (const float4*)d_in[1];
  const float4* vgt = (const float4*)d_in[2];
  const float4* pgt = (const float4*)d_in[3];
  const float* ldv = (const float*)d_in[4];
  const float* ldc = (const float*)d_in[5];

  double* acc = (double*)d_ws;
  float2* segsum = (float2*)((char*)d_ws + 64);

  hipMemsetAsync(d_ws, 0, 64, stream);                 // zero the 4 double accumulators
  kernA<<<NBLK, THREADS, 0, stream>>>(vel, cov, vgt, acc, segsum);
  kernB<<<NBLK, THREADS, 0, stream>>>(vel, pgt, segsum, acc);
  kernC<<<1, 64, 0, stream>>>(acc, ldv, ldc, (float*)d_out);
}

// Round 3
// 159.330 us; speedup vs baseline: 1.4540x; 1.4540x over previous
//
#include <hip/hip_runtime.h>

// Problem constants (fixed by setup_inputs)
static constexpr int B_ = 256;
static constexpr int T_ = 16384;
static constexpr int THREADS = 256;
static constexpr int SEG_T = 2048;                    // timesteps per block
static constexpr int NSEG = T_ / SEG_T;               // 8 segments per row
static constexpr int NBLK = B_ * NSEG;                // 2048 blocks
static constexpr int F4_PER_ROW = T_ * 2 / 4;         // 8192 float4 per b-row
static constexpr int F4_PER_SEG = SEG_T * 2 / 4;      // 1024 float4 per segment
static constexpr int F4_PER_THR = F4_PER_SEG / THREADS; // 4 float4 (8 timesteps) per thread

static constexpr float DTc    = 0.01f;
static constexpr float MINVAR = 0.01f;
static constexpr float EPSc   = 1e-6f;

// ws layout (all written every call, no memset needed):
//   [0]        float2 segsum[NBLK]   (16 KB)  per-segment vel sums (scan offsets)
//   [16 KB]    float  pLve[NBLK]     ( 8 KB)  per-block partial: sum (vel-vgt)^2
//   [24 KB]    float  pLc [NBLK]     ( 8 KB)  per-block partial: mahal+logdet
//   [32 KB]    float  pReg[NBLK]     ( 8 KB)  per-block partial: sum inv_sigma
//   [40 KB]    float  pPos[NBLK]     ( 8 KB)  per-block partial: sum (pos-pgt)^2

__device__ __forceinline__ float waveReduce(float v) {
#pragma unroll
  for (int d = 32; d > 0; d >>= 1) v += __shfl_down(v, d, 64);
  return v;
}

__device__ __forceinline__ double waveReduceD(double v) {
#pragma unroll
  for (int d = 32; d > 0; d >>= 1) v += __shfl_down(v, d, 64);
  return v;
}

__global__ __launch_bounds__(THREADS) void kernA(
    const float4* __restrict__ vel, const float4* __restrict__ cov,
    const float4* __restrict__ vgt, float2* __restrict__ segsum,
    float* __restrict__ pLve, float* __restrict__ pLc, float* __restrict__ pReg) {
  const int bid = blockIdx.x;
  const int b = bid >> 3, s = bid & (NSEG - 1);
  const int tid = threadIdx.x;
  const int base = b * F4_PER_ROW + s * F4_PER_SEG + tid * F4_PER_THR;

  float4 v[4], c[4], g[4];
#pragma unroll
  for (int i = 0; i < 4; ++i) v[i] = vel[base + i];
#pragma unroll
  for (int i = 0; i < 4; ++i) c[i] = cov[base + i];
#pragma unroll
  for (int i = 0; i < 4; ++i) g[i] = vgt[base + i];

  float sumx = 0.f, sumy = 0.f;       // chunk sum of vel (for scan)
  float lve = 0.f, lc = 0.f, reg = 0.f;
#pragma unroll
  for (int i = 0; i < 4; ++i) {
    sumx += v[i].x + v[i].z;
    sumy += v[i].y + v[i].w;
    {
      float dx = g[i].x - v[i].x, dy = g[i].y - v[i].y;
      float sqx = dx * dx, sqy = dy * dy;
      lve += sqx + sqy;
      float sx = fmaxf(__expf(c[i].x), MINVAR);
      float sy = fmaxf(__expf(c[i].y), MINVAR);
      float ix = 1.0f / sx, iy = 1.0f / sy;
      lc += ix * sqx + iy * sqy + __logf(sx * sy + EPSc);
      reg += ix + iy;
    }
    {
      float dx = g[i].z - v[i].z, dy = g[i].w - v[i].w;
      float sqx = dx * dx, sqy = dy * dy;
      lve += sqx + sqy;
      float sx = fmaxf(__expf(c[i].z), MINVAR);
      float sy = fmaxf(__expf(c[i].w), MINVAR);
      float ix = 1.0f / sx, iy = 1.0f / sy;
      lc += ix * sqx + iy * sqy + __logf(sx * sy + EPSc);
      reg += ix + iy;
    }
  }

  const int lane = tid & 63, wid = tid >> 6;
  float rx = waveReduce(sumx);
  float ry = waveReduce(sumy);
  float r1 = waveReduce(lve);
  float r2 = waveReduce(lc);
  float r3 = waveReduce(reg);
  __shared__ float sh[5][4];
  if (lane == 0) { sh[0][wid] = rx; sh[1][wid] = ry; sh[2][wid] = r1; sh[3][wid] = r2; sh[4][wid] = r3; }
  __syncthreads();
  if (tid == 0) {
    segsum[bid] = make_float2(sh[0][0] + sh[0][1] + sh[0][2] + sh[0][3],
                              sh[1][0] + sh[1][1] + sh[1][2] + sh[1][3]);
    pLve[bid] = sh[2][0] + sh[2][1] + sh[2][2] + sh[2][3];
    pLc [bid] = sh[3][0] + sh[3][1] + sh[3][2] + sh[3][3];
    pReg[bid] = sh[4][0] + sh[4][1] + sh[4][2] + sh[4][3];
  }
}

__global__ __launch_bounds__(THREADS) void kernB(
    const float4* __restrict__ vel, const float4* __restrict__ pgt,
    const float2* __restrict__ segsum, float* __restrict__ pPos) {
  const int bid = blockIdx.x;
  const int b = bid >> 3, s = bid & (NSEG - 1);
  const int tid = threadIdx.x;
  const int lane = tid & 63, wid = tid >> 6;
  const int base = b * F4_PER_ROW + s * F4_PER_SEG + tid * F4_PER_THR;

  float4 v[4], g[4];
#pragma unroll
  for (int i = 0; i < 4; ++i) v[i] = vel[base + i];
#pragma unroll
  for (int i = 0; i < 4; ++i) g[i] = pgt[base + i];

  float csx = 0.f, csy = 0.f;
#pragma unroll
  for (int i = 0; i < 4; ++i) { csx += v[i].x + v[i].z; csy += v[i].y + v[i].w; }

  // wave-level inclusive scan of per-thread chunk sums
  float ix = csx, iy = csy;
#pragma unroll
  for (int d = 1; d < 64; d <<= 1) {
    float tx = __shfl_up(ix, (unsigned)d, 64);
    float ty = __shfl_up(iy, (unsigned)d, 64);
    if (lane >= d) { ix += tx; iy += ty; }
  }
  __shared__ float2 wtot[4];
  if (lane == 63) wtot[wid] = make_float2(ix, iy);
  __syncthreads();

  float bx = ix - csx, by = iy - csy;   // exclusive within wave
  for (int w = 0; w < wid; ++w) { bx += wtot[w].x; by += wtot[w].y; }

  // add exclusive prefix of previous segments in this row
  const float2* ss = segsum + b * NSEG;
  for (int k = 0; k < s; ++k) { float2 t = ss[k]; bx += t.x; by += t.y; }

  const float2 v0 = ((const float2*)vel)[b * T_];

  float apos = 0.f;
#pragma unroll
  for (int i = 0; i < 4; ++i) {
    float px = DTc * (v0.x + bx), py = DTc * (v0.y + by);
    float ex = px - g[i].x, ey = py - g[i].y;
    apos += ex * ex + ey * ey;
    bx += v[i].x; by += v[i].y;
    px = DTc * (v0.x + bx); py = DTc * (v0.y + by);
    ex = px - g[i].z; ey = py - g[i].w;
    apos += ex * ex + ey * ey;
    bx += v[i].z; by += v[i].w;
  }

  float r = waveReduce(apos);
  __shared__ float sh[4];
  if (lane == 0) sh[wid] = r;
  __syncthreads();
  if (tid == 0) pPos[bid] = sh[0] + sh[1] + sh[2] + sh[3];
}

__global__ __launch_bounds__(THREADS) void kernC(
    const float* __restrict__ pLve, const float* __restrict__ pLc,
    const float* __restrict__ pReg, const float* __restrict__ pPos,
    const float* __restrict__ pldv, const float* __restrict__ pldc,
    float* __restrict__ out) {
  const int tid = threadIdx.x;
  const int lane = tid & 63, wid = tid >> 6;
  double a0 = 0.0, a1 = 0.0, a2 = 0.0, a3 = 0.0;
#pragma unroll
  for (int i = 0; i < NBLK / THREADS; ++i) {
    int idx = tid + i * THREADS;
    a0 += (double)pPos[idx];
    a1 += (double)pLve[idx];
    a2 += (double)pLc[idx];
    a3 += (double)pReg[idx];
  }
  a0 = waveReduceD(a0);
  a1 = waveReduceD(a1);
  a2 = waveReduceD(a2);
  a3 = waveReduceD(a3);
  __shared__ double sh[4][4];
  if (lane == 0) { sh[0][wid] = a0; sh[1][wid] = a1; sh[2][wid] = a2; sh[3][wid] = a3; }
  __syncthreads();
  if (tid == 0) {
    double pos_sq = sh[0][0] + sh[0][1] + sh[0][2] + sh[0][3];
    double vel_sq = sh[1][0] + sh[1][1] + sh[1][2] + sh[1][3];
    double lcs    = sh[2][0] + sh[2][1] + sh[2][2] + sh[2][3];
    double regs   = sh[3][0] + sh[3][1] + sh[3][2] + sh[3][3];
    const double NBT2 = (double)B_ * (double)T_ * 2.0;
    const double NBT  = (double)B_ * (double)T_;
    double lv  = (pos_sq + vel_sq) / NBT2;
    double lc  = 0.5 * lcs / NBT;
    double reg = regs / NBT;
    double ldv = (double)pldv[0], ldc = (double)pldc[0];
    double total = lv / (2.0 * exp(2.0 * ldv)) + lc / (2.0 * exp(2.0 * ldc))
                 + ldv + ldc + 0.01 * reg;
    out[0] = (float)total;
  }
}

extern "C" void kernel_launch(void* const* d_in, const int* in_sizes, int n_in,
                              void* d_out, int out_size, void* d_ws, size_t ws_size,
                              hipStream_t stream) {
  const float4* vel = (const float4*)d_in[0];
  const float4* cov = (const float4*)d_in[1];
  const float4* vgt = (const float4*)d_in[2];
  const float4* pgt = (const float4*)d_in[3];
  const float* ldv = (const float*)d_in[4];
  const float* ldc = (const float*)d_in[5];

  char* ws = (char*)d_ws;
  float2* segsum = (float2*)ws;                         // 16 KB
  float* pLve = (float*)(ws + 16 * 1024);               //  8 KB
  float* pLc  = (float*)(ws + 24 * 1024);               //  8 KB
  float* pReg = (float*)(ws + 32 * 1024);               //  8 KB
  float* pPos = (float*)(ws + 40 * 1024);               //  8 KB

  kernA<<<NBLK, THREADS, 0, stream>>>(vel, cov, vgt, segsum, pLve, pLc, pReg);
  kernB<<<NBLK, THREADS, 0, stream>>>(vel, pgt, segsum, pPos);
  kernC<<<1, THREADS, 0, stream>>>(pLve, pLc, pReg, pPos, ldv, ldc, (float*)d_out);
}

// Round 4
// 158.254 us; speedup vs baseline: 1.4639x; 1.0068x over previous
//
#include <hip/hip_runtime.h>

// Problem constants (fixed by setup_inputs)
static constexpr int B_ = 256;
static constexpr int T_ = 16384;
static constexpr int THREADS = 256;
static constexpr int SEG_T = 2048;                    // timesteps per block
static constexpr int NSEG = T_ / SEG_T;               // 8 segments per row
static constexpr int NBLK = B_ * NSEG;                // 2048 blocks
static constexpr int F4_PER_ROW = T_ * 2 / 4;         // 8192 float4 per b-row
static constexpr int F4_PER_SEG = SEG_T * 2 / 4;      // 1024 float4 per segment

static constexpr float DTc    = 0.01f;
static constexpr float MINVAR = 0.01f;
static constexpr float EPSc   = 1e-6f;

// ws layout (all written every call, no memset needed):
//   [0]        float2 segsum[NBLK]   (16 KB)  per-segment vel sums (scan offsets)
//   [16 KB]    float  pLve[NBLK]     ( 8 KB)
//   [24 KB]    float  pLc [NBLK]     ( 8 KB)
//   [32 KB]    float  pReg[NBLK]     ( 8 KB)
//   [40 KB]    float  pPos[NBLK]     ( 8 KB)

__device__ __forceinline__ float waveReduce(float v) {
#pragma unroll
  for (int d = 32; d > 0; d >>= 1) v += __shfl_down(v, d, 64);
  return v;
}

__device__ __forceinline__ double waveReduceD(double v) {
#pragma unroll
  for (int d = 32; d > 0; d >>= 1) v += __shfl_down(v, d, 64);
  return v;
}

// Coalesced: lane-contiguous float4 loads (tid + k*THREADS). Sums are order-free.
__global__ __launch_bounds__(THREADS) void kernA(
    const float4* __restrict__ vel, const float4* __restrict__ cov,
    const float4* __restrict__ vgt, float2* __restrict__ segsum,
    float* __restrict__ pLve, float* __restrict__ pLc, float* __restrict__ pReg) {
  const int bid = blockIdx.x;
  const int b = bid >> 3, s = bid & (NSEG - 1);
  const int tid = threadIdx.x;
  const int base = b * F4_PER_ROW + s * F4_PER_SEG + tid;

  float4 v[4], c[4], g[4];
#pragma unroll
  for (int i = 0; i < 4; ++i) v[i] = vel[base + i * THREADS];
#pragma unroll
  for (int i = 0; i < 4; ++i) c[i] = cov[base + i * THREADS];
#pragma unroll
  for (int i = 0; i < 4; ++i) g[i] = vgt[base + i * THREADS];

  float sumx = 0.f, sumy = 0.f;
  float lve = 0.f, lc = 0.f, reg = 0.f;
#pragma unroll
  for (int i = 0; i < 4; ++i) {
    sumx += v[i].x + v[i].z;
    sumy += v[i].y + v[i].w;
    {
      float dx = g[i].x - v[i].x, dy = g[i].y - v[i].y;
      float sqx = dx * dx, sqy = dy * dy;
      lve += sqx + sqy;
      float sx = fmaxf(__expf(c[i].x), MINVAR);
      float sy = fmaxf(__expf(c[i].y), MINVAR);
      float ix = 1.0f / sx, iy = 1.0f / sy;
      lc += ix * sqx + iy * sqy + __logf(sx * sy + EPSc);
      reg += ix + iy;
    }
    {
      float dx = g[i].z - v[i].z, dy = g[i].w - v[i].w;
      float sqx = dx * dx, sqy = dy * dy;
      lve += sqx + sqy;
      float sx = fmaxf(__expf(c[i].z), MINVAR);
      float sy = fmaxf(__expf(c[i].w), MINVAR);
      float ix = 1.0f / sx, iy = 1.0f / sy;
      lc += ix * sqx + iy * sqy + __logf(sx * sy + EPSc);
      reg += ix + iy;
    }
  }

  const int lane = tid & 63, wid = tid >> 6;
  float rx = waveReduce(sumx);
  float ry = waveReduce(sumy);
  float r1 = waveReduce(lve);
  float r2 = waveReduce(lc);
  float r3 = waveReduce(reg);
  __shared__ float sh[5][4];
  if (lane == 0) { sh[0][wid] = rx; sh[1][wid] = ry; sh[2][wid] = r1; sh[3][wid] = r2; sh[4][wid] = r3; }
  __syncthreads();
  if (tid == 0) {
    segsum[bid] = make_float2(sh[0][0] + sh[0][1] + sh[0][2] + sh[0][3],
                              sh[1][0] + sh[1][1] + sh[1][2] + sh[1][3]);
    pLve[bid] = sh[2][0] + sh[2][1] + sh[2][2] + sh[2][3];
    pLc [bid] = sh[3][0] + sh[3][1] + sh[3][2] + sh[3][3];
    pReg[bid] = sh[4][0] + sh[4][1] + sh[4][2] + sh[4][3];
  }
}

// Coalesced loads + LDS scan at float4 granularity (1024 entries).
__global__ __launch_bounds__(THREADS) void kernB(
    const float4* __restrict__ vel, const float4* __restrict__ pgt,
    const float2* __restrict__ segsum, float* __restrict__ pPos) {
  const int bid = blockIdx.x;
  const int b = bid >> 3, s = bid & (NSEG - 1);
  const int tid = threadIdx.x;
  const int lane = tid & 63, wid = tid >> 6;
  const int base = b * F4_PER_ROW + s * F4_PER_SEG + tid;

  float4 v[4], g[4];
#pragma unroll
  for (int i = 0; i < 4; ++i) v[i] = vel[base + i * THREADS];
#pragma unroll
  for (int i = 0; i < 4; ++i) g[i] = pgt[base + i * THREADS];

  __shared__ float2 ps[F4_PER_SEG];   // 8 KB: per-float4 (x,y) sums -> exclusive prefixes
#pragma unroll
  for (int i = 0; i < 4; ++i)
    ps[tid + i * THREADS] = make_float2(v[i].x + v[i].z, v[i].y + v[i].w);
  __syncthreads();

  // Thread t scans entries 4t..4t+3 (consecutive), then wave+block combine.
  float2 e0 = ps[4 * tid + 0], e1 = ps[4 * tid + 1], e2 = ps[4 * tid + 2], e3 = ps[4 * tid + 3];
  float i1x = e0.x + e1.x,   i1y = e0.y + e1.y;
  float i2x = i1x + e2.x,    i2y = i1y + e2.y;
  float tx  = i2x + e3.x,    ty  = i2y + e3.y;     // thread total

  float sxv = tx, syv = ty;                        // wave inclusive scan of totals
#pragma unroll
  for (int d = 1; d < 64; d <<= 1) {
    float ux = __shfl_up(sxv, (unsigned)d, 64);
    float uy = __shfl_up(syv, (unsigned)d, 64);
    if (lane >= d) { sxv += ux; syv += uy; }
  }
  __shared__ float2 wt[4];
  if (lane == 63) wt[wid] = make_float2(sxv, syv);
  __syncthreads();

  float offx = sxv - tx, offy = syv - ty;          // exclusive within wave
  for (int w = 0; w < wid; ++w) { offx += wt[w].x; offy += wt[w].y; }

  // write back exclusive prefixes
  ps[4 * tid + 0] = make_float2(offx,        offy);
  ps[4 * tid + 1] = make_float2(offx + e0.x, offy + e0.y);
  ps[4 * tid + 2] = make_float2(offx + i1x,  offy + i1y);
  ps[4 * tid + 3] = make_float2(offx + i2x,  offy + i2y);
  __syncthreads();

  // row offset: exclusive prefix of previous segments in this row
  float rxo = 0.f, ryo = 0.f;
  const float2* ss = segsum + b * NSEG;
  for (int k = 0; k < s; ++k) { float2 t2 = ss[k]; rxo += t2.x; ryo += t2.y; }

  const float2 v0 = ((const float2*)vel)[b * T_];

  float apos = 0.f;
#pragma unroll
  for (int i = 0; i < 4; ++i) {
    float2 p = ps[tid + i * THREADS];
    float bx = p.x + rxo, by = p.y + ryo;
    float px = DTc * (v0.x + bx), py = DTc * (v0.y + by);
    float ex = px - g[i].x, ey = py - g[i].y;
    apos += ex * ex + ey * ey;
    bx += v[i].x; by += v[i].y;
    px = DTc * (v0.x + bx); py = DTc * (v0.y + by);
    ex = px - g[i].z; ey = py - g[i].w;
    apos += ex * ex + ey * ey;
  }

  float r = waveReduce(apos);
  __shared__ float sh[4];
  if (lane == 0) sh[wid] = r;
  __syncthreads();
  if (tid == 0) pPos[bid] = sh[0] + sh[1] + sh[2] + sh[3];
}

__global__ __launch_bounds__(THREADS) void kernC(
    const float* __restrict__ pLve, const float* __restrict__ pLc,
    const float* __restrict__ pReg, const float* __restrict__ pPos,
    const float* __restrict__ pldv, const float* __restrict__ pldc,
    float* __restrict__ out) {
  const int tid = threadIdx.x;
  const int lane = tid & 63, wid = tid >> 6;
  double a0 = 0.0, a1 = 0.0, a2 = 0.0, a3 = 0.0;
#pragma unroll
  for (int i = 0; i < NBLK / THREADS; ++i) {
    int idx = tid + i * THREADS;
    a0 += (double)pPos[idx];
    a1 += (double)pLve[idx];
    a2 += (double)pLc[idx];
    a3 += (double)pReg[idx];
  }
  a0 = waveReduceD(a0);
  a1 = waveReduceD(a1);
  a2 = waveReduceD(a2);
  a3 = waveReduceD(a3);
  __shared__ double sh[4][4];
  if (lane == 0) { sh[0][wid] = a0; sh[1][wid] = a1; sh[2][wid] = a2; sh[3][wid] = a3; }
  __syncthreads();
  if (tid == 0) {
    double pos_sq = sh[0][0] + sh[0][1] + sh[0][2] + sh[0][3];
    double vel_sq = sh[1][0] + sh[1][1] + sh[1][2] + sh[1][3];
    double lcs    = sh[2][0] + sh[2][1] + sh[2][2] + sh[2][3];
    double regs   = sh[3][0] + sh[3][1] + sh[3][2] + sh[3][3];
    const double NBT2 = (double)B_ * (double)T_ * 2.0;
    const double NBT  = (double)B_ * (double)T_;
    double lv  = (pos_sq + vel_sq) / NBT2;
    double lc  = 0.5 * lcs / NBT;
    double reg = regs / NBT;
    double ldv = (double)pldv[0], ldc = (double)pldc[0];
    double total = lv / (2.0 * exp(2.0 * ldv)) + lc / (2.0 * exp(2.0 * ldc))
                 + ldv + ldc + 0.01 * reg;
    out[0] = (float)total;
  }
}

extern "C" void kernel_launch(void* const* d_in, const int* in_sizes, int n_in,
                              void* d_out, int out_size, void* d_ws, size_t ws_size,
                              hipStream_t stream) {
  const float4* vel = (const float4*)d_in[0];
  const float4* cov = (const float4*)d_in[1];
  const float4* vgt = (const float4*)d_in[2];
  const float4* pgt = (const float4*)d_in[3];
  const float* ldv = (const float*)d_in[4];
  const float* ldc = (const float*)d_in[5];

  char* ws = (char*)d_ws;
  float2* segsum = (float2*)ws;                         // 16 KB
  float* pLve = (float*)(ws + 16 * 1024);               //  8 KB
  float* pLc  = (float*)(ws + 24 * 1024);               //  8 KB
  float* pReg = (float*)(ws + 32 * 1024);               //  8 KB
  float* pPos = (float*)(ws + 40 * 1024);               //  8 KB

  kernA<<<NBLK, THREADS, 0, stream>>>(vel, cov, vgt, segsum, pLve, pLc, pReg);
  kernB<<<NBLK, THREADS, 0, stream>>>(vel, pgt, segsum, pPos);
  kernC<<<1, THREADS, 0, stream>>>(pLve, pLc, pReg, pPos, ldv, ldc, (float*)d_out);
}